// Round 5
// baseline (175.001 us; speedup 1.0000x reference)
//
#include <hip/hip_runtime.h>

#define NCELLS 1024
#define LDIM   30
#define GDIM   10000
#define NBATCH 64
#define GPB    256     // genes per block (4 waves x 64)
#define WGENES 64      // genes per wave
#define WCAP   64      // per-wave cell list cap (binomial(1024,1/64): mean 16, 64 = +12 sigma)

typedef unsigned int u32;
typedef unsigned long long u64;

// grid = (NBATCH, ceil(G/GPB)), block = 256, one gene per thread.
// A[b,g,:] is consumed ONLY by the thread owning gene g -> no cross-thread
// reuse -> A is loaded DIRECTLY into registers (no LDS staging, no DMA).
// LDS = 1 KB (wlist only). No __syncthreads anywhere.
//
// R2-R4 FAILURE ROOT CAUSE (fixed here): myid/mysf feed v_readlane, whose
// uses were all after the divergent `if (g>=GDIM) return`. The compiler
// could sink those loads past the return, so in the boundary wave
// (blockIdx.y==39) inactive lanes never loaded their values and readlane
// returned stale regalloc-dependent garbage (run-to-run-different absmax).
// Fix: NO early return at all (stores predicated on `valid` instead), plus
// a volatile asm pin to force materialization under full exec.
__global__ __launch_bounds__(256, 6) void decoder_kernel(
    const float* __restrict__ z,      // [N,L]     f32
    const void*  __restrict__ cand1,  // [N]  bcov or sf (classified on device)
    const void*  __restrict__ cand2,  // [N]  the other one
    const float* __restrict__ W,      // [L,G]     f32
    const float* __restrict__ A,      // [NB,G,L]  f32
    const float* __restrict__ Bb,     // [NB,G]    f32
    const float* __restrict__ px,     // [G]       f32
    float* __restrict__ out)          // [N*G + G] f32
{
    const int b    = blockIdx.x;
    const int tid  = threadIdx.x;
    const int lane = tid & 63;
    const int wid  = __builtin_amdgcn_readfirstlane(tid >> 6);  // 0..3 uniform
    const int g    = blockIdx.y * GPB + wid * WGENES + lane;
    const bool valid = (g < GDIM);
    const int gc   = valid ? g : GDIM - 1;   // clamp: dup loads, stores masked

    __shared__ int wlist[4][WCAP];   // 1024 B total

    // ---- classify the two 1024-elem inputs (one load + ballot) ----
    // int32 0..63 words all < 64u; uniform-[0,1) f32 bit patterns are not.
    const u32 probe = ((const u32*)cand1)[lane];
    const bool c1_is_int = __all(probe < 64u);
    const int*   bcov = c1_is_int ? (const int*)cand1   : (const int*)cand2;
    const float* sf   = c1_is_int ? (const float*)cand2 : (const float*)cand1;

    // ---- fused row directly in registers: m[l] = W[l,g] + A[b,g,l] ----
    // A row base = 120 B * (b*G+gc): 8B-aligned -> float2 loads; across the
    // 15 loads the wave consumes every byte of its 7.5 KB chunk (L1-resident
    // after the first instruction's line fills). W loads fully coalesced.
    float m[LDIM];
    {
        const float2* arow = (const float2*)(A + ((size_t)b * GDIM + gc) * LDIM);
        #pragma unroll
        for (int j = 0; j < LDIM / 2; j++) {
            const float2 av = arow[j];
            m[2 * j]     = W[(size_t)(2 * j)     * GDIM + gc] + av.x;
            m[2 * j + 1] = W[(size_t)(2 * j + 1) * GDIM + gc] + av.y;
        }
    }
    const float h3  = Bb[(size_t)b * GDIM + gc];
    const float pxv = px[gc];

    // ---- wave-private cell scan: ballot prefix compaction, no atomics ----
    wlist[wid][lane] = 0;                       // garbage-safe default id
    int cnt = 0;                                // wave-uniform running count
    const u64 below = (1ull << lane) - 1ull;    // lane 63: 0x7fff... (ok)
    for (int i0 = 0; i0 < NCELLS; i0 += 64) {
        const int v = bcov[i0 + lane];
        const u64 mb = __ballot(v == b);
        if (v == b) {
            const int pos = cnt + (int)__popcll(mb & below);
            if (pos < WCAP) wlist[wid][pos] = i0 + lane;
        }
        cnt += (int)__popcll(mb);
    }
    const int total = cnt < WCAP ? cnt : WCAP;

    // cell ids + size factors into registers: one per lane, broadcast later
    // via v_readlane. Computed under FULL exec (no divergence before/after),
    // pinned so the compiler cannot sink or predicate these loads.
    int   myid = wlist[wid][lane];              // same-wave ds ops, lgkm-ordered
    float mysf = sf[myid];                      // gather, ids in [0,1024)
    asm volatile("" : "+v"(myid), "+v"(mysf)); // materialize HERE, full exec

    // second output: inverse_dispersion = exp(px_r), f32 at offset N*G
    if (valid && b == 0) out[(size_t)NCELLS * GDIM + g] = __expf(pxv);

    int c = 0;
    for (; c + 4 <= total; c += 4) {   // 4 cells x 2 chains = 8 indep FMA chains
        const int cell0 = __builtin_amdgcn_readlane(myid, c);
        const int cell1 = __builtin_amdgcn_readlane(myid, c + 1);
        const int cell2 = __builtin_amdgcn_readlane(myid, c + 2);
        const int cell3 = __builtin_amdgcn_readlane(myid, c + 3);
        const float s0 = __int_as_float(__builtin_amdgcn_readlane(__float_as_int(mysf), c));
        const float s1 = __int_as_float(__builtin_amdgcn_readlane(__float_as_int(mysf), c + 1));
        const float s2 = __int_as_float(__builtin_amdgcn_readlane(__float_as_int(mysf), c + 2));
        const float s3 = __int_as_float(__builtin_amdgcn_readlane(__float_as_int(mysf), c + 3));
        const float* z0 = z + (size_t)cell0 * LDIM;   // uniform -> s_load
        const float* z1 = z + (size_t)cell1 * LDIM;
        const float* z2 = z + (size_t)cell2 * LDIM;
        const float* z3 = z + (size_t)cell3 * LDIM;
        float a0 = h3, b0 = 0.f, a1 = h3, b1 = 0.f;
        float a2 = h3, b2 = 0.f, a3 = h3, b3 = 0.f;
        #pragma unroll
        for (int l = 0; l < LDIM; l += 2) {
            a0 = fmaf(m[l],     z0[l],     a0);
            b0 = fmaf(m[l + 1], z0[l + 1], b0);
            a1 = fmaf(m[l],     z1[l],     a1);
            b1 = fmaf(m[l + 1], z1[l + 1], b1);
            a2 = fmaf(m[l],     z2[l],     a2);
            b2 = fmaf(m[l + 1], z2[l + 1], b2);
            a3 = fmaf(m[l],     z3[l],     a3);
            b3 = fmaf(m[l + 1], z3[l + 1], b3);
        }
        float x0 = a0 + b0, x1 = a1 + b1, x2 = a2 + b2, x3 = a3 + b3;
        // stable softplus: max(x,0) + log(1 + exp(-|x|))
        float p0 = fmaxf(x0, 0.f) + __logf(1.f + __expf(-fabsf(x0)));
        float p1 = fmaxf(x1, 0.f) + __logf(1.f + __expf(-fabsf(x1)));
        float p2 = fmaxf(x2, 0.f) + __logf(1.f + __expf(-fabsf(x2)));
        float p3 = fmaxf(x3, 0.f) + __logf(1.f + __expf(-fabsf(x3)));
        if (valid) {
            __builtin_nontemporal_store(p0 * s0, &out[(size_t)cell0 * GDIM + g]);
            __builtin_nontemporal_store(p1 * s1, &out[(size_t)cell1 * GDIM + g]);
            __builtin_nontemporal_store(p2 * s2, &out[(size_t)cell2 * GDIM + g]);
            __builtin_nontemporal_store(p3 * s3, &out[(size_t)cell3 * GDIM + g]);
        }
    }
    for (; c < total; c++) {              // 0..3 tail cells
        const int cell0 = __builtin_amdgcn_readlane(myid, c);
        const float s0 = __int_as_float(__builtin_amdgcn_readlane(__float_as_int(mysf), c));
        const float* z0 = z + (size_t)cell0 * LDIM;
        float a0 = h3, b0 = 0.f;
        #pragma unroll
        for (int l = 0; l < LDIM; l += 2) {
            a0 = fmaf(m[l],     z0[l],     a0);
            b0 = fmaf(m[l + 1], z0[l + 1], b0);
        }
        float x0 = a0 + b0;
        float p0 = fmaxf(x0, 0.f) + __logf(1.f + __expf(-fabsf(x0)));
        if (valid)
            __builtin_nontemporal_store(p0 * s0, &out[(size_t)cell0 * GDIM + g]);
    }
}

extern "C" void kernel_launch(void* const* d_in, const int* in_sizes, int n_in,
                              void* d_out, int out_size, void* d_ws, size_t ws_size,
                              hipStream_t stream) {
    // Bind inputs by element count (robust to ordering); the two 1024-element
    // inputs (bcov / size_factor) are disambiguated on device by content.
    const float* z  = nullptr;   // 30720
    const float* W  = nullptr;   // 300000
    const float* A  = nullptr;   // 19200000
    const float* Bb = nullptr;   // 640000
    const float* px = nullptr;   // 10000
    const void*  p1024[2] = {nullptr, nullptr};
    int n1024 = 0;
    for (int i = 0; i < n_in; i++) {
        switch (in_sizes[i]) {
            case NCELLS * LDIM:        z  = (const float*)d_in[i]; break;
            case LDIM * GDIM:          W  = (const float*)d_in[i]; break;
            case NBATCH * GDIM * LDIM: A  = (const float*)d_in[i]; break;
            case NBATCH * GDIM:        Bb = (const float*)d_in[i]; break;
            case GDIM:                 px = (const float*)d_in[i]; break;
            case NCELLS:
                if (n1024 < 2) p1024[n1024] = d_in[i];
                n1024++;
                break;
            default: break;
        }
    }
    if (!z || !W || !A || !Bb || !px || n1024 != 2) {  // fallback: dict order
        z  = (const float*)d_in[0];
        p1024[0] = d_in[1];
        p1024[1] = d_in[2];
        W  = (const float*)d_in[3];
        A  = (const float*)d_in[4];
        Bb = (const float*)d_in[5];
        px = (const float*)d_in[6];
    }
    float* out = (float*)d_out;

    decoder_kernel<<<dim3(NBATCH, (GDIM + GPB - 1) / GPB), 256, 0, stream>>>(
        z, p1024[0], p1024[1], W, A, Bb, px, out);
}

// Round 7
// 161.092 us; speedup vs baseline: 1.0863x; 1.0863x over previous
//
#include <hip/hip_runtime.h>

#define NCELLS 1024
#define LDIM   30
#define GDIM   10000
#define NBATCH 64
#define GPB    256     // genes per block (4 waves x 64)
#define WCAP   64      // per-wave cell list cap (binomial(1024,1/64): mean 16, +12 sigma)

typedef unsigned int u32;
typedef unsigned long long u64;

#define GLOBAL_AS __attribute__((address_space(1)))
#define LDS_AS    __attribute__((address_space(3)))

// grid = (NBATCH, ceil(G/GPB)), block = 256, one gene per thread.
//
// R5 LESSON (perf): direct per-lane float2 loads of A (120B lane stride) hit
// ~64 distinct cache lines per instruction -> ~16us of L1-pipe serialization.
// A MUST be staged coalesced: async global_load_lds (16B/lane, 1KB/instr),
// exactly the R1 structure that measured 53.6us.
// R2-R4 LESSON (correctness): values feeding v_readlane must be materialized
// under FULL exec and never live across a divergent return -> no early return
// anywhere; stores predicated on `valid`; asm pin on myid/mysf.
// All DMA instructions execute at full-wave granularity (tail round masks
// whole waves 2,3, never partial lanes); OOB clamped branchlessly.
__global__ __launch_bounds__(256, 5) void decoder_kernel(
    const float* __restrict__ z,      // [N,L]     f32
    const void*  __restrict__ cand1,  // [N]  bcov or sf (classified on device)
    const void*  __restrict__ cand2,  // [N]  the other one
    const float* __restrict__ W,      // [L,G]     f32
    const float* __restrict__ A,      // [NB,G,L]  f32
    const float* __restrict__ Bb,     // [NB,G]    f32
    const float* __restrict__ px,     // [G]       f32
    float* __restrict__ out)          // [N*G + G] f32
{
    const int b    = blockIdx.x;
    const int tid  = threadIdx.x;
    const int lane = tid & 63;
    const int wid  = __builtin_amdgcn_readfirstlane(tid >> 6);  // 0..3 uniform
    const int g    = blockIdx.y * GPB + tid;
    const bool valid = (g < GDIM);
    const int gc   = valid ? g : GDIM - 1;   // clamp: dup loads, stores masked

    __shared__ __align__(16) float a_sh[GPB * LDIM];  // 30720 B
    __shared__ int wlist[4][WCAP];                    //  1024 B -> 31744 total

    // ---- 1. async A-tile staging: 1920 float4 = 30720 B, coalesced ----
    // 7 rounds x 256 lanes x 16B (28672 B) + 1 tail round by waves 0-1 only
    // (whole-wave exec; 128 lanes x 16B = 2048 B). LDS dest = wave-uniform
    // base (float offset k*1024 + wid*256); HW adds lane*16.
    const size_t abase = ((size_t)b * GDIM + (size_t)blockIdx.y * GPB) * LDIM;
    const size_t atot  = (size_t)NBATCH * GDIM * LDIM;
    #pragma unroll
    for (int k = 0; k < 7; k++) {
        size_t gidx = abase + (size_t)(k * 256 + tid) * 4;
        if (gidx + 4 > atot) gidx = atot - 4;   // branchless clamp (b=63 tail)
        __builtin_amdgcn_global_load_lds(
            (const GLOBAL_AS void*)(A + gidx),
            (LDS_AS void*)(a_sh + k * 1024 + wid * 256), 16, 0, 0);
    }
    if (tid < 128) {   // waves 0,1 fully active; waves 2,3 fully skipped
        size_t gidx = abase + (size_t)(1792 + tid) * 4;
        if (gidx + 4 > atot) gidx = atot - 4;
        __builtin_amdgcn_global_load_lds(
            (const GLOBAL_AS void*)(A + gidx),
            (LDS_AS void*)(a_sh + 7168 + wid * 256), 16, 0, 0);
    }

    // ---- 2. classify the two 1024-elem inputs (one load + ballot) ----
    // int32 0..63 words all < 64u; uniform-[0,1) f32 bit patterns are not.
    const u32 probe = ((const u32*)cand1)[lane];
    const bool c1_is_int = __all(probe < 64u);
    const int*   bcov = c1_is_int ? (const int*)cand1   : (const int*)cand2;
    const float* sf   = c1_is_int ? (const float*)cand2 : (const float*)cand1;

    // ---- 3. wave-private cell scan (overlaps DMA): int4 loads + ballot ----
    wlist[wid][lane] = 0;                       // garbage-safe default id
    int cnt = 0;                                // wave-uniform running count
    const u64 below = (1ull << lane) - 1ull;
    const int4* b4 = (const int4*)bcov;         // input buffers 16B-aligned
    #pragma unroll
    for (int i0 = 0; i0 < 4; i0++) {
        const int4 v = b4[i0 * 64 + lane];      // coalesced 1KB
        const int base = i0 * 256 + lane * 4;
        #pragma unroll
        for (int j = 0; j < 4; j++) {
            const int vj = (j == 0) ? v.x : (j == 1) ? v.y : (j == 2) ? v.z : v.w;
            const u64 mb = __ballot(vj == b);
            if (vj == b) {
                const int pos = cnt + (int)__popcll(mb & below);
                if (pos < WCAP) wlist[wid][pos] = base + j;
            }
            cnt += (int)__popcll(mb);
        }
    }
    const int total = cnt < WCAP ? cnt : WCAP;

    // ---- 4. W row / bias / px loads also overlap the DMA ----
    float m[LDIM];
    #pragma unroll
    for (int l = 0; l < LDIM; l++) m[l] = W[(size_t)l * GDIM + gc];  // coalesced
    const float h3  = Bb[(size_t)b * GDIM + gc];
    const float pxv = px[gc];

    __syncthreads();   // drains DMA vmcnt + scan ds_writes (R1-proven path)

    // cell ids + size factors into registers under FULL exec, pinned so the
    // compiler can neither sink nor predicate them (v_readlane reads any lane).
    int   myid = wlist[wid][lane];
    float mysf = sf[myid];                      // gather, ids in [0,1024)
    asm volatile("" : "+v"(myid), "+v"(mysf));  // materialize HERE, full exec

    // fused row: m[l] += a_sh[tid][l]; 120B rows -> ds_read_b64, bank stride
    // 30 -> only 2-way aliasing (free on CDNA4)
    {
        const float2* ar = (const float2*)(a_sh + tid * LDIM);
        #pragma unroll
        for (int j = 0; j < LDIM / 2; j++) {
            const float2 w2 = ar[j];
            m[2 * j]     += w2.x;
            m[2 * j + 1] += w2.y;
        }
    }

    // second output: inverse_dispersion = exp(px_r), f32 at offset N*G
    if (valid && b == 0) out[(size_t)NCELLS * GDIM + g] = __expf(pxv);

    int c = 0;
    for (; c + 4 <= total; c += 4) {   // 4 cells x 2 chains = 8 indep FMA chains
        const int cell0 = __builtin_amdgcn_readlane(myid, c);
        const int cell1 = __builtin_amdgcn_readlane(myid, c + 1);
        const int cell2 = __builtin_amdgcn_readlane(myid, c + 2);
        const int cell3 = __builtin_amdgcn_readlane(myid, c + 3);
        const float s0 = __int_as_float(__builtin_amdgcn_readlane(__float_as_int(mysf), c));
        const float s1 = __int_as_float(__builtin_amdgcn_readlane(__float_as_int(mysf), c + 1));
        const float s2 = __int_as_float(__builtin_amdgcn_readlane(__float_as_int(mysf), c + 2));
        const float s3 = __int_as_float(__builtin_amdgcn_readlane(__float_as_int(mysf), c + 3));
        const float* z0 = z + (size_t)cell0 * LDIM;   // uniform -> s_load
        const float* z1 = z + (size_t)cell1 * LDIM;
        const float* z2 = z + (size_t)cell2 * LDIM;
        const float* z3 = z + (size_t)cell3 * LDIM;
        float a0 = h3, b0 = 0.f, a1 = h3, b1 = 0.f;
        float a2 = h3, b2 = 0.f, a3 = h3, b3 = 0.f;
        #pragma unroll
        for (int l = 0; l < LDIM; l += 2) {
            a0 = fmaf(m[l],     z0[l],     a0);
            b0 = fmaf(m[l + 1], z0[l + 1], b0);
            a1 = fmaf(m[l],     z1[l],     a1);
            b1 = fmaf(m[l + 1], z1[l + 1], b1);
            a2 = fmaf(m[l],     z2[l],     a2);
            b2 = fmaf(m[l + 1], z2[l + 1], b2);
            a3 = fmaf(m[l],     z3[l],     a3);
            b3 = fmaf(m[l + 1], z3[l + 1], b3);
        }
        float x0 = a0 + b0, x1 = a1 + b1, x2 = a2 + b2, x3 = a3 + b3;
        // stable softplus: max(x,0) + log(1 + exp(-|x|))
        float p0 = fmaxf(x0, 0.f) + __logf(1.f + __expf(-fabsf(x0)));
        float p1 = fmaxf(x1, 0.f) + __logf(1.f + __expf(-fabsf(x1)));
        float p2 = fmaxf(x2, 0.f) + __logf(1.f + __expf(-fabsf(x2)));
        float p3 = fmaxf(x3, 0.f) + __logf(1.f + __expf(-fabsf(x3)));
        if (valid) {
            __builtin_nontemporal_store(p0 * s0, &out[(size_t)cell0 * GDIM + g]);
            __builtin_nontemporal_store(p1 * s1, &out[(size_t)cell1 * GDIM + g]);
            __builtin_nontemporal_store(p2 * s2, &out[(size_t)cell2 * GDIM + g]);
            __builtin_nontemporal_store(p3 * s3, &out[(size_t)cell3 * GDIM + g]);
        }
    }
    for (; c < total; c++) {              // 0..3 tail cells
        const int cell0 = __builtin_amdgcn_readlane(myid, c);
        const float s0 = __int_as_float(__builtin_amdgcn_readlane(__float_as_int(mysf), c));
        const float* z0 = z + (size_t)cell0 * LDIM;
        float a0 = h3, b0 = 0.f;
        #pragma unroll
        for (int l = 0; l < LDIM; l += 2) {
            a0 = fmaf(m[l],     z0[l],     a0);
            b0 = fmaf(m[l + 1], z0[l + 1], b0);
        }
        float x0 = a0 + b0;
        float p0 = fmaxf(x0, 0.f) + __logf(1.f + __expf(-fabsf(x0)));
        if (valid)
            __builtin_nontemporal_store(p0 * s0, &out[(size_t)cell0 * GDIM + g]);
    }
}

extern "C" void kernel_launch(void* const* d_in, const int* in_sizes, int n_in,
                              void* d_out, int out_size, void* d_ws, size_t ws_size,
                              hipStream_t stream) {
    // Bind inputs by element count (robust to ordering); the two 1024-element
    // inputs (bcov / size_factor) are disambiguated on device by content.
    const float* z  = nullptr;   // 30720
    const float* W  = nullptr;   // 300000
    const float* A  = nullptr;   // 19200000
    const float* Bb = nullptr;   // 640000
    const float* px = nullptr;   // 10000
    const void*  p1024[2] = {nullptr, nullptr};
    int n1024 = 0;
    for (int i = 0; i < n_in; i++) {
        switch (in_sizes[i]) {
            case NCELLS * LDIM:        z  = (const float*)d_in[i]; break;
            case LDIM * GDIM:          W  = (const float*)d_in[i]; break;
            case NBATCH * GDIM * LDIM: A  = (const float*)d_in[i]; break;
            case NBATCH * GDIM:        Bb = (const float*)d_in[i]; break;
            case GDIM:                 px = (const float*)d_in[i]; break;
            case NCELLS:
                if (n1024 < 2) p1024[n1024] = d_in[i];
                n1024++;
                break;
            default: break;
        }
    }
    if (!z || !W || !A || !Bb || !px || n1024 != 2) {  // fallback: dict order
        z  = (const float*)d_in[0];
        p1024[0] = d_in[1];
        p1024[1] = d_in[2];
        W  = (const float*)d_in[3];
        A  = (const float*)d_in[4];
        Bb = (const float*)d_in[5];
        px = (const float*)d_in[6];
    }
    float* out = (float*)d_out;

    decoder_kernel<<<dim3(NBATCH, (GDIM + GPB - 1) / GPB), 256, 0, stream>>>(
        z, p1024[0], p1024[1], W, A, Bb, px, out);
}